// Round 4
// baseline (360.238 us; speedup 1.0000x reference)
//
#include <hip/hip_runtime.h>
#include <stdint.h>

#define LQ 8192
#define LK 8192
#define DD 128
#define SCALE 0.08838834764831845f   // 1/sqrt(128)

typedef __attribute__((ext_vector_type(8))) __bf16 bf16x8;
typedef __attribute__((ext_vector_type(4))) float f32x4;

// async global->LDS, 16B per lane; LDS dest = wave-uniform base + lane*16
#define GLOAD16(gp, lp) __builtin_amdgcn_global_load_lds( \
    (const __attribute__((address_space(1))) unsigned int*)(gp), \
    (__attribute__((address_space(3))) unsigned int*)(lp), 16, 0, 0)

__device__ __forceinline__ unsigned short f2bf(float f) {
    unsigned u = __builtin_bit_cast(unsigned, f);
    return (unsigned short)((u + 0x7FFFu + ((u >> 16) & 1u)) >> 16);  // RNE; inputs have no NaN
}

// ---------------- prep: q,k -> bf16 (scale folded into q); zero out-region and l ----------------
__global__ void k_prep(const float* __restrict__ q, const float* __restrict__ k,
                       unsigned short* __restrict__ qb, unsigned short* __restrict__ kb,
                       float* __restrict__ outp, float* __restrict__ wsl) {
    int bid = blockIdx.x, tid = threadIdx.x;
    if (bid < 2048) {
        const float4* src = (bid < 1024) ? (const float4*)q : (const float4*)k;
        unsigned short* dst = (bid < 1024) ? qb : kb;
        float s = (bid < 1024) ? SCALE : 1.0f;
        int i = (bid & 1023) * 256 + tid;
        float4 v = src[i];
        ushort4 o;
        o.x = f2bf(v.x * s); o.y = f2bf(v.y * s); o.z = f2bf(v.z * s); o.w = f2bf(v.w * s);
        ((ushort4*)dst)[i] = o;
    } else if (bid < 3072) {
        int i = (bid - 2048) * 256 + tid;                 // 1M floats of out
        ((float4*)outp)[i] = make_float4(0.f, 0.f, 0.f, 0.f);
    } else {
        int i = (bid - 3072) * 256 + tid;                 // 8192 floats of l
        ((float4*)wsl)[i] = make_float4(0.f, 0.f, 0.f, 0.f);
    }
}

// ---------------- V [8192][128] fp32 -> vbT [128][8192] bf16 ----------------
__global__ void k_vt(const float* __restrict__ v, unsigned short* __restrict__ vbT) {
    int bid = blockIdx.x, tid = threadIdx.x;
    int nt = bid >> 1, dt = bid & 1;
    int nb = nt * 64, db = dt * 64;
    __shared__ unsigned short tile[64 * 73];              // pad 73 breaks transpose bank conflicts
    for (int it = 0; it < 4; ++it) {
        int idx = it * 256 + tid;                         // 0..1023
        int n = idx >> 4, d4 = (idx & 15) * 4;
        float4 x = *(const float4*)(v + (size_t)(nb + n) * 128 + db + d4);
        unsigned short* t0 = &tile[n * 73 + d4];
        t0[0] = f2bf(x.x); t0[1] = f2bf(x.y); t0[2] = f2bf(x.z); t0[3] = f2bf(x.w);
    }
    __syncthreads();
    for (int it = 0; it < 2; ++it) {
        int idx = it * 256 + tid;                         // 0..511
        int d = idx >> 3, n8 = (idx & 7) * 8;
        unsigned e[8];
        #pragma unroll
        for (int j = 0; j < 8; ++j) e[j] = tile[(n8 + j) * 73 + d];
        uint4 o;
        o.x = e[0] | (e[1] << 16); o.y = e[2] | (e[3] << 16);
        o.z = e[4] | (e[5] << 16); o.w = e[6] | (e[7] << 16);
        *(uint4*)(vbT + (size_t)(db + d) * 8192 + nb + n8) = o;
    }
}

// ---------------- pass 1: l[row] = sum_n exp(qk) ----------------
// T1 XCD swizzle: dispatch order round-robins XCDs, so map orig%8 -> sp strip.
// Each XCD's L2 then holds only its strip's K (256KB) + qb (2MB) -> L2-resident.
__launch_bounds__(256)
__global__ void k_sums(const unsigned short* __restrict__ qb, const unsigned short* __restrict__ kb,
                       float* __restrict__ wsl) {
    int obid = blockIdx.x, tid = threadIdx.x;
    int bid = ((obid & 7) << 7) | (obid >> 3);            // bijective: XCD x <- sp strip x
    int rb = bid & 127, sp = bid >> 7;
    int r0 = rb * 64, cbase = sp * 1024;
    int lane = tid & 63, wave = tid >> 6, l15 = lane & 15, quad = lane >> 4;
    int swz = (l15 & 7) << 4;                             // read-side swizzle
    __shared__ unsigned short ks[2][64 * 128];            // 32 KB double buffer
    __shared__ float lpart[4][64];

    int srow = lane >> 4;                                 // staging: row within 4-row group
    int scol = (lane & 15) << 4;                          // staging: 16B chunk within 256B row

    // ---- prologue: stage Q rows [r0, r0+64) into ks[0], hoist fragments ----
    #pragma unroll
    for (int it = 0; it < 4; ++it) {
        int i = wave * 4 + it;
        int row = i * 4 + srow;
        const char* gp = (const char*)qb + (((size_t)(r0 + row)) << 8)
                         + (scol ^ ((row & 7) << 4));
        GLOAD16(gp, (char*)&ks[0][0] + i * 1024);
    }
    __syncthreads();
    bf16x8 qf[4][4];
    #pragma unroll
    for (int t = 0; t < 4; ++t)
        #pragma unroll
        for (int s = 0; s < 4; ++s)
            qf[t][s] = *(const bf16x8*)((const char*)&ks[0][0] + (t * 16 + l15) * 256
                         + ((s * 64 + quad * 16) ^ swz));
    __syncthreads();                                      // qf reads done before K overwrites ks[0]

    // ---- prologue: stage K chunk 0 into ks[0] ----
    #pragma unroll
    for (int it = 0; it < 4; ++it) {
        int i = wave * 4 + it;
        int row = i * 4 + srow;
        const char* gp = (const char*)kb + (((size_t)(cbase + row)) << 8)
                         + (scol ^ ((row & 7) << 4));
        GLOAD16(gp, (char*)&ks[0][0] + i * 1024);
    }
    __syncthreads();                                      // chunk 0 landed for all waves

    float lacc[4] = {0.f, 0.f, 0.f, 0.f};
    for (int c = 0; c < 16; ++c) {
        int cur = c & 1, nxt = cur ^ 1;
        if (c < 15) {
            int n0 = cbase + (c + 1) * 64;
            #pragma unroll
            for (int it = 0; it < 4; ++it) {
                int i = wave * 4 + it;
                int row = i * 4 + srow;
                const char* gp = (const char*)kb + (((size_t)(n0 + row)) << 8)
                                 + (scol ^ ((row & 7) << 4));
                GLOAD16(gp, (char*)&ks[nxt][0] + i * 1024);
            }
        }
        __builtin_amdgcn_sched_barrier(0);                // pin gload issue before compute

        f32x4 z = {0.f, 0.f, 0.f, 0.f};
        f32x4 acc[4] = {z, z, z, z};
        #pragma unroll
        for (int s = 0; s < 4; ++s) {
            bf16x8 af = *(const bf16x8*)((const char*)&ks[cur][0] + (wave * 16 + l15) * 256
                          + ((s * 64 + quad * 16) ^ swz));
            #pragma unroll
            for (int t = 0; t < 4; ++t)
                acc[t] = __builtin_amdgcn_mfma_f32_16x16x32_bf16(af, qf[t][s], acc[t], 0, 0, 0);
        }
        #pragma unroll
        for (int t = 0; t < 4; ++t)
            lacc[t] += __expf(acc[t][0]) + __expf(acc[t][1]) + __expf(acc[t][2]) + __expf(acc[t][3]);

        // reads of ks[cur] retired (lgkm) + next chunk landed (vmcnt) -> one barrier
        asm volatile("s_waitcnt lgkmcnt(0)" ::: "memory");
        if (c < 15) asm volatile("s_waitcnt vmcnt(0)" ::: "memory");
        __builtin_amdgcn_sched_barrier(0);
        __builtin_amdgcn_s_barrier();
    }
    #pragma unroll
    for (int t = 0; t < 4; ++t) {
        lacc[t] += __shfl_xor(lacc[t], 16);
        lacc[t] += __shfl_xor(lacc[t], 32);
    }
    if (lane < 16) {
        #pragma unroll
        for (int t = 0; t < 4; ++t) lpart[wave][t * 16 + lane] = lacc[t];
    }
    __syncthreads();
    if (tid < 64) {
        float s = lpart[0][tid] + lpart[1][tid] + lpart[2][tid] + lpart[3][tid];
        atomicAdd(&wsl[r0 + tid], s);
    }
}

// ---------------- pass 2: att = exp(qk)/l, out += att @ V ----------------
// T1 XCD swizzle (K/V strip L2-resident per XCD) + non-temporal att stores
// (write-once stream must not evict K/V/Q from L2).
__launch_bounds__(256)
__global__ void k_att(const unsigned short* __restrict__ qb, const unsigned short* __restrict__ kb,
                      const unsigned short* __restrict__ vbT, const float* __restrict__ wsl,
                      float* __restrict__ outp, float* __restrict__ att) {
    int obid = blockIdx.x, tid = threadIdx.x;
    int bid = ((obid & 7) << 7) | (obid >> 3);            // bijective: XCD x <- sp strip x
    int rb = bid & 127, sp = bid >> 7;
    int r0 = rb * 64, cbase = sp * 1024;
    int lane = tid & 63, wave = tid >> 6, l15 = lane & 15, quad = lane >> 4;
    int swz = (l15 & 7) << 4;
    __shared__ unsigned short ks[2][64 * 128];            // 32 KB K double buffer
    __shared__ unsigned short vt[2][128 * 64];            // 32 KB V^T double buffer
    __shared__ unsigned short pp[64 * 72];                // 9 KB P chunk (VALU-written, padded)

    int srowK = lane >> 4, scolK = (lane & 15) << 4;      // 256B-row staging
    int srowV = lane >> 3, scolV = (lane & 7) << 4;       // 128B-row staging

    // rl loads first so the prologue __syncthreads drains them out of the vmcnt queue
    float rl[4];
    #pragma unroll
    for (int t = 0; t < 4; ++t) rl[t] = 1.0f / wsl[r0 + t * 16 + l15];

    // ---- prologue: stage Q into ks[0], hoist fragments ----
    #pragma unroll
    for (int it = 0; it < 4; ++it) {
        int i = wave * 4 + it;
        int row = i * 4 + srowK;
        const char* gp = (const char*)qb + (((size_t)(r0 + row)) << 8)
                         + (scolK ^ ((row & 7) << 4));
        GLOAD16(gp, (char*)&ks[0][0] + i * 1024);
    }
    __syncthreads();
    bf16x8 qf[4][4];
    #pragma unroll
    for (int t = 0; t < 4; ++t)
        #pragma unroll
        for (int s = 0; s < 4; ++s)
            qf[t][s] = *(const bf16x8*)((const char*)&ks[0][0] + (t * 16 + l15) * 256
                         + ((s * 64 + quad * 16) ^ swz));
    __syncthreads();                                      // qf done before K chunk 0 reuses ks[0]

    // ---- prologue: stage K,V chunk 0 ----
    #pragma unroll
    for (int it = 0; it < 4; ++it) {
        int i = wave * 4 + it;
        int row = i * 4 + srowK;
        const char* gp = (const char*)kb + (((size_t)(cbase + row)) << 8)
                         + (scolK ^ ((row & 7) << 4));
        GLOAD16(gp, (char*)&ks[0][0] + i * 1024);
    }
    #pragma unroll
    for (int it = 0; it < 4; ++it) {
        int i = wave * 4 + it;
        int row = i * 8 + srowV;
        const char* gp = (const char*)vbT + (((size_t)row) << 14) + ((size_t)cbase << 1)
                         + (scolV ^ ((row & 7) << 4));
        GLOAD16(gp, (char*)&vt[0][0] + i * 1024);
    }
    __syncthreads();                                      // chunk 0 landed

    f32x4 z = {0.f, 0.f, 0.f, 0.f};
    f32x4 oacc[8] = {z, z, z, z, z, z, z, z};

    for (int c = 0; c < 16; ++c) {
        int cur = c & 1, nxt = cur ^ 1;
        int n0 = cbase + c * 64;
        if (c < 15) {
            int n1 = n0 + 64;
            #pragma unroll
            for (int it = 0; it < 4; ++it) {              // K rows [n1, n1+64)
                int i = wave * 4 + it;
                int row = i * 4 + srowK;
                const char* gp = (const char*)kb + (((size_t)(n1 + row)) << 8)
                                 + (scolK ^ ((row & 7) << 4));
                GLOAD16(gp, (char*)&ks[nxt][0] + i * 1024);
            }
            #pragma unroll
            for (int it = 0; it < 4; ++it) {              // V^T rows d=0..127, cols [n1, n1+64)
                int i = wave * 4 + it;
                int row = i * 8 + srowV;
                const char* gp = (const char*)vbT + (((size_t)row) << 14) + ((size_t)n1 << 1)
                                 + (scolV ^ ((row & 7) << 4));
                GLOAD16(gp, (char*)&vt[nxt][0] + i * 1024);
            }
        }
        __builtin_amdgcn_sched_barrier(0);                // gloads issue first -> vmcnt(4) math holds

        // ---- QK^T for chunk c ----
        f32x4 acc[4] = {z, z, z, z};
        #pragma unroll
        for (int s = 0; s < 4; ++s) {
            bf16x8 af = *(const bf16x8*)((const char*)&ks[cur][0] + (wave * 16 + l15) * 256
                          + ((s * 64 + quad * 16) ^ swz));
            #pragma unroll
            for (int t = 0; t < 4; ++t)
                acc[t] = __builtin_amdgcn_mfma_f32_16x16x32_bf16(af, qf[t][s], acc[t], 0, 0, 0);
        }
        // D[n][m]: n = n0 + wave*16 + quad*4 + reg (contiguous att cols), m = r0 + t*16 + l15
        #pragma unroll
        for (int t = 0; t < 4; ++t) {
            float e0 = __expf(acc[t][0]) * rl[t];
            float e1 = __expf(acc[t][1]) * rl[t];
            float e2 = __expf(acc[t][2]) * rl[t];
            float e3 = __expf(acc[t][3]) * rl[t];
            f32x4 o4 = {e0, e1, e2, e3};
            __builtin_nontemporal_store(o4,
                (f32x4*)(att + (size_t)(r0 + t * 16 + l15) * 8192 + n0 + wave * 16 + quad * 4));
            ushort4 pv; pv.x = f2bf(e0); pv.y = f2bf(e1); pv.z = f2bf(e2); pv.w = f2bf(e3);
            *(ushort4*)&pp[(t * 16 + l15) * 72 + wave * 16 + quad * 4] = pv;
        }
        asm volatile("s_waitcnt lgkmcnt(0)" ::: "memory"); // pp visible
        __builtin_amdgcn_sched_barrier(0);
        __builtin_amdgcn_s_barrier();                      // barrier 1: pp ready

        // ---- PV for chunk c ----
        #pragma unroll
        for (int s2 = 0; s2 < 2; ++s2) {
            bf16x8 pf = *(const bf16x8*)&pp[(wave * 16 + l15) * 72 + s2 * 32 + quad * 8];
            #pragma unroll
            for (int dt = 0; dt < 8; ++dt) {
                bf16x8 vf = *(const bf16x8*)((const char*)&vt[cur][0] + (dt * 16 + l15) * 128
                              + ((s2 * 64 + quad * 16) ^ swz));
                oacc[dt] = __builtin_amdgcn_mfma_f32_16x16x32_bf16(pf, vf, oacc[dt], 0, 0, 0);
            }
        }
        // reads of cur buffers retired; next chunk's 8 gloads landed (allow 4 att stores
        // of this chunk to stay in flight across the barrier)
        asm volatile("s_waitcnt lgkmcnt(0)" ::: "memory");
        if (c < 15) asm volatile("s_waitcnt vmcnt(4)" ::: "memory");
        __builtin_amdgcn_sched_barrier(0);
        __builtin_amdgcn_s_barrier();                      // barrier 2: safe to overwrite bufs
    }
    // D rows = m_local = quad*4+reg (of wave's 16-row tile), cols = d = dt*16 + l15
    #pragma unroll
    for (int dt = 0; dt < 8; ++dt)
        #pragma unroll
        for (int r = 0; r < 4; ++r)
            atomicAdd(outp + (size_t)(r0 + wave * 16 + quad * 4 + r) * 128 + dt * 16 + l15,
                      oacc[dt][r]);
}

extern "C" void kernel_launch(void* const* d_in, const int* in_sizes, int n_in,
                              void* d_out, int out_size, void* d_ws, size_t ws_size,
                              hipStream_t stream) {
    const float* q = (const float*)d_in[0];
    const float* k = (const float*)d_in[1];
    const float* v = (const float*)d_in[2];
    float* outp = (float*)d_out;
    float* att = outp + (size_t)LQ * DD;
    // ws layout: qb(2MB) | kb(2MB) | vbT(2MB) | l(32KB)  -> requires ws_size >= 6.32 MB
    unsigned short* qb = (unsigned short*)d_ws;
    unsigned short* kb = qb + (size_t)LQ * DD;
    unsigned short* vbT = kb + (size_t)LK * DD;
    float* wsl = (float*)(vbT + (size_t)LK * DD);

    hipLaunchKernelGGL(k_prep, dim3(3080), dim3(256), 0, stream, q, k, qb, kb, outp, wsl);
    hipLaunchKernelGGL(k_vt,   dim3(256),  dim3(256), 0, stream, v, vbT);
    hipLaunchKernelGGL(k_sums, dim3(1024), dim3(256), 0, stream, qb, kb, wsl);
    hipLaunchKernelGGL(k_att,  dim3(1024), dim3(256), 0, stream, qb, kb, vbT, wsl, outp, att);
}

// Round 5
// 335.748 us; speedup vs baseline: 1.0729x; 1.0729x over previous
//
#include <hip/hip_runtime.h>
#include <stdint.h>

#define LQ 8192
#define LK 8192
#define DD 128
#define SCALE 0.08838834764831845f   // 1/sqrt(128)

typedef __attribute__((ext_vector_type(8))) __bf16 bf16x8;
typedef __attribute__((ext_vector_type(4))) float f32x4;

// async global->LDS, 16B per lane; LDS dest = wave-uniform base + lane*16
#define GLOAD16(gp, lp) __builtin_amdgcn_global_load_lds( \
    (const __attribute__((address_space(1))) unsigned int*)(gp), \
    (__attribute__((address_space(3))) unsigned int*)(lp), 16, 0, 0)

__device__ __forceinline__ unsigned short f2bf(float f) {
    unsigned u = __builtin_bit_cast(unsigned, f);
    return (unsigned short)((u + 0x7FFFu + ((u >> 16) & 1u)) >> 16);  // RNE; inputs have no NaN
}

// ---------------- prep: q,k -> bf16 (scale folded into q); zero out-region and l ----------------
__global__ void k_prep(const float* __restrict__ q, const float* __restrict__ k,
                       unsigned short* __restrict__ qb, unsigned short* __restrict__ kb,
                       float* __restrict__ outp, float* __restrict__ wsl) {
    int bid = blockIdx.x, tid = threadIdx.x;
    if (bid < 2048) {
        const float4* src = (bid < 1024) ? (const float4*)q : (const float4*)k;
        unsigned short* dst = (bid < 1024) ? qb : kb;
        float s = (bid < 1024) ? SCALE : 1.0f;
        int i = (bid & 1023) * 256 + tid;
        float4 v = src[i];
        ushort4 o;
        o.x = f2bf(v.x * s); o.y = f2bf(v.y * s); o.z = f2bf(v.z * s); o.w = f2bf(v.w * s);
        ((ushort4*)dst)[i] = o;
    } else if (bid < 3072) {
        int i = (bid - 2048) * 256 + tid;                 // 1M floats of out
        ((float4*)outp)[i] = make_float4(0.f, 0.f, 0.f, 0.f);
    } else {
        int i = (bid - 3072) * 256 + tid;                 // 8192 floats of l
        ((float4*)wsl)[i] = make_float4(0.f, 0.f, 0.f, 0.f);
    }
}

// ---------------- V [8192][128] fp32 -> vbT [128][8192] bf16 ----------------
__global__ void k_vt(const float* __restrict__ v, unsigned short* __restrict__ vbT) {
    int bid = blockIdx.x, tid = threadIdx.x;
    int nt = bid >> 1, dt = bid & 1;
    int nb = nt * 64, db = dt * 64;
    __shared__ unsigned short tile[64 * 73];              // pad 73 breaks transpose bank conflicts
    for (int it = 0; it < 4; ++it) {
        int idx = it * 256 + tid;                         // 0..1023
        int n = idx >> 4, d4 = (idx & 15) * 4;
        float4 x = *(const float4*)(v + (size_t)(nb + n) * 128 + db + d4);
        unsigned short* t0 = &tile[n * 73 + d4];
        t0[0] = f2bf(x.x); t0[1] = f2bf(x.y); t0[2] = f2bf(x.z); t0[3] = f2bf(x.w);
    }
    __syncthreads();
    for (int it = 0; it < 2; ++it) {
        int idx = it * 256 + tid;                         // 0..511
        int d = idx >> 3, n8 = (idx & 7) * 8;
        unsigned e[8];
        #pragma unroll
        for (int j = 0; j < 8; ++j) e[j] = tile[(n8 + j) * 73 + d];
        uint4 o;
        o.x = e[0] | (e[1] << 16); o.y = e[2] | (e[3] << 16);
        o.z = e[4] | (e[5] << 16); o.w = e[6] | (e[7] << 16);
        *(uint4*)(vbT + (size_t)(db + d) * 8192 + nb + n8) = o;
    }
}

// ---------------- pass 1: l[row] = sum_n exp(qk) ----------------
// Double-buffered K, STAGE(c+1) before compute(c), one raw barrier per chunk.
__launch_bounds__(256)
__global__ void k_sums(const unsigned short* __restrict__ qb, const unsigned short* __restrict__ kb,
                       float* __restrict__ wsl) {
    int bid = blockIdx.x, tid = threadIdx.x;
    int rb = bid & 127, sp = bid >> 7;
    int r0 = rb * 64, cbase = sp * 1024;
    int lane = tid & 63, wave = tid >> 6, l15 = lane & 15, quad = lane >> 4;
    int swz = (l15 & 7) << 4;                             // read-side swizzle
    __shared__ unsigned short ks[2][64 * 128];            // 32 KB double buffer
    __shared__ float lpart[4][64];

    int srow = lane >> 4;                                 // staging: row within 4-row group
    int scol = (lane & 15) << 4;                          // staging: 16B chunk within 256B row

    // ---- prologue: stage Q rows [r0, r0+64) into ks[0], hoist fragments ----
    #pragma unroll
    for (int it = 0; it < 4; ++it) {
        int i = wave * 4 + it;
        int row = i * 4 + srow;
        const char* gp = (const char*)qb + (((size_t)(r0 + row)) << 8)
                         + (scol ^ ((row & 7) << 4));
        GLOAD16(gp, (char*)&ks[0][0] + i * 1024);
    }
    __syncthreads();
    bf16x8 qf[4][4];
    #pragma unroll
    for (int t = 0; t < 4; ++t)
        #pragma unroll
        for (int s = 0; s < 4; ++s)
            qf[t][s] = *(const bf16x8*)((const char*)&ks[0][0] + (t * 16 + l15) * 256
                         + ((s * 64 + quad * 16) ^ swz));
    __syncthreads();                                      // qf reads done before K overwrites ks[0]

    // ---- prologue: stage K chunk 0 into ks[0] ----
    #pragma unroll
    for (int it = 0; it < 4; ++it) {
        int i = wave * 4 + it;
        int row = i * 4 + srow;
        const char* gp = (const char*)kb + (((size_t)(cbase + row)) << 8)
                         + (scol ^ ((row & 7) << 4));
        GLOAD16(gp, (char*)&ks[0][0] + i * 1024);
    }
    __syncthreads();                                      // chunk 0 landed for all waves

    float lacc[4] = {0.f, 0.f, 0.f, 0.f};
    for (int c = 0; c < 16; ++c) {
        int cur = c & 1, nxt = cur ^ 1;
        if (c < 15) {
            int n0 = cbase + (c + 1) * 64;
            #pragma unroll
            for (int it = 0; it < 4; ++it) {
                int i = wave * 4 + it;
                int row = i * 4 + srow;
                const char* gp = (const char*)kb + (((size_t)(n0 + row)) << 8)
                                 + (scol ^ ((row & 7) << 4));
                GLOAD16(gp, (char*)&ks[nxt][0] + i * 1024);
            }
        }
        __builtin_amdgcn_sched_barrier(0);                // pin gload issue before compute

        f32x4 z = {0.f, 0.f, 0.f, 0.f};
        f32x4 acc[4] = {z, z, z, z};
        #pragma unroll
        for (int s = 0; s < 4; ++s) {
            bf16x8 af = *(const bf16x8*)((const char*)&ks[cur][0] + (wave * 16 + l15) * 256
                          + ((s * 64 + quad * 16) ^ swz));
            #pragma unroll
            for (int t = 0; t < 4; ++t)
                acc[t] = __builtin_amdgcn_mfma_f32_16x16x32_bf16(af, qf[t][s], acc[t], 0, 0, 0);
        }
        #pragma unroll
        for (int t = 0; t < 4; ++t)
            lacc[t] += __expf(acc[t][0]) + __expf(acc[t][1]) + __expf(acc[t][2]) + __expf(acc[t][3]);

        // reads of ks[cur] retired (lgkm) + next chunk landed (vmcnt) -> one barrier
        asm volatile("s_waitcnt lgkmcnt(0)" ::: "memory");
        if (c < 15) asm volatile("s_waitcnt vmcnt(0)" ::: "memory");
        __builtin_amdgcn_sched_barrier(0);
        __builtin_amdgcn_s_barrier();
    }
    #pragma unroll
    for (int t = 0; t < 4; ++t) {
        lacc[t] += __shfl_xor(lacc[t], 16);
        lacc[t] += __shfl_xor(lacc[t], 32);
    }
    if (lane < 16) {
        #pragma unroll
        for (int t = 0; t < 4; ++t) lpart[wave][t * 16 + lane] = lacc[t];
    }
    __syncthreads();
    if (tid < 64) {
        float s = lpart[0][tid] + lpart[1][tid] + lpart[2][tid] + lpart[3][tid];
        atomicAdd(&wsl[r0 + tid], s);
    }
}

// ---------------- pass 2: att = exp(qk)/l, out += att @ V ----------------
// sp-split 4 (was 16): 512 blocks, each handles 2048 cols (32 chunks).
// Same 2-block/CU residency (73 KB LDS caps at 2 anyway); out-atomics drop
// 16.8M -> 4.2M with 4-way (was 16-way) same-address contention.
__launch_bounds__(256)
__global__ void k_att(const unsigned short* __restrict__ qb, const unsigned short* __restrict__ kb,
                      const unsigned short* __restrict__ vbT, const float* __restrict__ wsl,
                      float* __restrict__ outp, float* __restrict__ att) {
    int bid = blockIdx.x, tid = threadIdx.x;
    int rb = bid & 127, sp = bid >> 7;                    // sp in [0,4)
    int r0 = rb * 64, cbase = sp * 2048;
    int lane = tid & 63, wave = tid >> 6, l15 = lane & 15, quad = lane >> 4;
    int swz = (l15 & 7) << 4;
    __shared__ unsigned short ks[2][64 * 128];            // 32 KB K double buffer
    __shared__ unsigned short vt[2][128 * 64];            // 32 KB V^T double buffer
    __shared__ unsigned short pp[64 * 72];                // 9 KB P chunk (VALU-written, padded)

    int srowK = lane >> 4, scolK = (lane & 15) << 4;      // 256B-row staging
    int srowV = lane >> 3, scolV = (lane & 7) << 4;       // 128B-row staging

    // rl loads first so the prologue __syncthreads drains them out of the vmcnt queue
    float rl[4];
    #pragma unroll
    for (int t = 0; t < 4; ++t) rl[t] = 1.0f / wsl[r0 + t * 16 + l15];

    // ---- prologue: stage Q into ks[0], hoist fragments ----
    #pragma unroll
    for (int it = 0; it < 4; ++it) {
        int i = wave * 4 + it;
        int row = i * 4 + srowK;
        const char* gp = (const char*)qb + (((size_t)(r0 + row)) << 8)
                         + (scolK ^ ((row & 7) << 4));
        GLOAD16(gp, (char*)&ks[0][0] + i * 1024);
    }
    __syncthreads();
    bf16x8 qf[4][4];
    #pragma unroll
    for (int t = 0; t < 4; ++t)
        #pragma unroll
        for (int s = 0; s < 4; ++s)
            qf[t][s] = *(const bf16x8*)((const char*)&ks[0][0] + (t * 16 + l15) * 256
                         + ((s * 64 + quad * 16) ^ swz));
    __syncthreads();                                      // qf done before K chunk 0 reuses ks[0]

    // ---- prologue: stage K,V chunk 0 ----
    #pragma unroll
    for (int it = 0; it < 4; ++it) {
        int i = wave * 4 + it;
        int row = i * 4 + srowK;
        const char* gp = (const char*)kb + (((size_t)(cbase + row)) << 8)
                         + (scolK ^ ((row & 7) << 4));
        GLOAD16(gp, (char*)&ks[0][0] + i * 1024);
    }
    #pragma unroll
    for (int it = 0; it < 4; ++it) {
        int i = wave * 4 + it;
        int row = i * 8 + srowV;
        const char* gp = (const char*)vbT + (((size_t)row) << 14) + ((size_t)cbase << 1)
                         + (scolV ^ ((row & 7) << 4));
        GLOAD16(gp, (char*)&vt[0][0] + i * 1024);
    }
    __syncthreads();                                      // chunk 0 landed

    f32x4 z = {0.f, 0.f, 0.f, 0.f};
    f32x4 oacc[8] = {z, z, z, z, z, z, z, z};

    for (int c = 0; c < 32; ++c) {
        int cur = c & 1, nxt = cur ^ 1;
        int n0 = cbase + c * 64;
        if (c < 31) {
            int n1 = n0 + 64;
            #pragma unroll
            for (int it = 0; it < 4; ++it) {              // K rows [n1, n1+64)
                int i = wave * 4 + it;
                int row = i * 4 + srowK;
                const char* gp = (const char*)kb + (((size_t)(n1 + row)) << 8)
                                 + (scolK ^ ((row & 7) << 4));
                GLOAD16(gp, (char*)&ks[nxt][0] + i * 1024);
            }
            #pragma unroll
            for (int it = 0; it < 4; ++it) {              // V^T rows d=0..127, cols [n1, n1+64)
                int i = wave * 4 + it;
                int row = i * 8 + srowV;
                const char* gp = (const char*)vbT + (((size_t)row) << 14) + ((size_t)n1 << 1)
                                 + (scolV ^ ((row & 7) << 4));
                GLOAD16(gp, (char*)&vt[nxt][0] + i * 1024);
            }
        }
        __builtin_amdgcn_sched_barrier(0);                // gloads issue first -> vmcnt(4) math holds

        // ---- QK^T for chunk c ----
        f32x4 acc[4] = {z, z, z, z};
        #pragma unroll
        for (int s = 0; s < 4; ++s) {
            bf16x8 af = *(const bf16x8*)((const char*)&ks[cur][0] + (wave * 16 + l15) * 256
                          + ((s * 64 + quad * 16) ^ swz));
            #pragma unroll
            for (int t = 0; t < 4; ++t)
                acc[t] = __builtin_amdgcn_mfma_f32_16x16x32_bf16(af, qf[t][s], acc[t], 0, 0, 0);
        }
        // D[n][m]: n = n0 + wave*16 + quad*4 + reg (contiguous att cols), m = r0 + t*16 + l15
        #pragma unroll
        for (int t = 0; t < 4; ++t) {
            float e0 = __expf(acc[t][0]) * rl[t];
            float e1 = __expf(acc[t][1]) * rl[t];
            float e2 = __expf(acc[t][2]) * rl[t];
            float e3 = __expf(acc[t][3]) * rl[t];
            *(float4*)(att + (size_t)(r0 + t * 16 + l15) * 8192 + n0 + wave * 16 + quad * 4)
                = make_float4(e0, e1, e2, e3);
            ushort4 pv; pv.x = f2bf(e0); pv.y = f2bf(e1); pv.z = f2bf(e2); pv.w = f2bf(e3);
            *(ushort4*)&pp[(t * 16 + l15) * 72 + wave * 16 + quad * 4] = pv;
        }
        asm volatile("s_waitcnt lgkmcnt(0)" ::: "memory"); // pp visible
        __builtin_amdgcn_sched_barrier(0);
        __builtin_amdgcn_s_barrier();                      // barrier 1: pp ready

        // ---- PV for chunk c ----
        #pragma unroll
        for (int s2 = 0; s2 < 2; ++s2) {
            bf16x8 pf = *(const bf16x8*)&pp[(wave * 16 + l15) * 72 + s2 * 32 + quad * 8];
            #pragma unroll
            for (int dt = 0; dt < 8; ++dt) {
                bf16x8 vf = *(const bf16x8*)((const char*)&vt[cur][0] + (dt * 16 + l15) * 128
                              + ((s2 * 64 + quad * 16) ^ swz));
                oacc[dt] = __builtin_amdgcn_mfma_f32_16x16x32_bf16(pf, vf, oacc[dt], 0, 0, 0);
            }
        }
        // reads of cur buffers retired; next chunk's 8 gloads landed (allow 4 att stores
        // of this chunk to stay in flight across the barrier)
        asm volatile("s_waitcnt lgkmcnt(0)" ::: "memory");
        if (c < 31) asm volatile("s_waitcnt vmcnt(4)" ::: "memory");
        __builtin_amdgcn_sched_barrier(0);
        __builtin_amdgcn_s_barrier();                      // barrier 2: safe to overwrite bufs
    }
    // D rows = m_local = quad*4+reg (of wave's 16-row tile), cols = d = dt*16 + l15
    #pragma unroll
    for (int dt = 0; dt < 8; ++dt)
        #pragma unroll
        for (int r = 0; r < 4; ++r)
            atomicAdd(outp + (size_t)(r0 + wave * 16 + quad * 4 + r) * 128 + dt * 16 + l15,
                      oacc[dt][r]);
}

extern "C" void kernel_launch(void* const* d_in, const int* in_sizes, int n_in,
                              void* d_out, int out_size, void* d_ws, size_t ws_size,
                              hipStream_t stream) {
    const float* q = (const float*)d_in[0];
    const float* k = (const float*)d_in[1];
    const float* v = (const float*)d_in[2];
    float* outp = (float*)d_out;
    float* att = outp + (size_t)LQ * DD;
    // ws layout: qb(2MB) | kb(2MB) | vbT(2MB) | l(32KB)  -> requires ws_size >= 6.32 MB
    unsigned short* qb = (unsigned short*)d_ws;
    unsigned short* kb = qb + (size_t)LQ * DD;
    unsigned short* vbT = kb + (size_t)LK * DD;
    float* wsl = (float*)(vbT + (size_t)LK * DD);

    hipLaunchKernelGGL(k_prep, dim3(3080), dim3(256), 0, stream, q, k, qb, kb, outp, wsl);
    hipLaunchKernelGGL(k_vt,   dim3(256),  dim3(256), 0, stream, v, vbT);
    hipLaunchKernelGGL(k_sums, dim3(1024), dim3(256), 0, stream, qb, kb, wsl);
    hipLaunchKernelGGL(k_att,  dim3(512),  dim3(256), 0, stream, qb, kb, vbT, wsl, outp, att);
}